// Round 14
// baseline (951.282 us; speedup 1.0000x reference)
//
#include <hip/hip_runtime.h>
#include <hip/hip_bf16.h>
#include <math.h>

#define NN 10000
#define NE 160000
#define NG 64
#define NT 5
#define NL 4
#define ADL 2.833213344056216f
#define AROW 1632            // A row: 1500 agg | 36 zero | 75 h | 21 zero

typedef __attribute__((ext_vector_type(8))) short bf16x8;
typedef __attribute__((ext_vector_type(4))) float f32x4;

// ws layout (float offsets)
#define OFF_H      0
#define OFF_HC     750000
#define OFF_P      1500000     // bf16 P
#define OFF_Q      5250000     // bf16 Q
#define OFF_A      9000000     // bf16 A matrix [10000][1632] = 8.16M floats
#define OFF_BT     17200000    // bf16 BT [3][80][1632] = 195840 floats
#define OFF_BIASC  17400000
#define OFF_RLUT   24000000
#define OFF_INVDEG 24006000
#define OFF_AMP    24016000
#define OFF_ATT    24026000
#define OFF_STATS  24036000
#define OFF_GPOOL  24036160
#define OFF_INT    24118960

__device__ __forceinline__ float bf2f(__hip_bfloat16 v){ return __bfloat162float(v); }

__global__ void k_zero_cnt(int* cnt){
    int i = blockIdx.x*256 + threadIdx.x;
    if (i < NN) cnt[i] = 0;
}

// zero A pad columns (1500..1535, 1611..1631) once per launch
__global__ void k_zpad(__hip_bfloat16* __restrict__ A){
    int idx = blockIdx.x*256 + threadIdx.x;
    if (idx >= NN*57) return;
    int n = idx/57, c = idx - n*57;
    int k = (c < 36) ? 1500 + c : 1611 + (c - 36);
    A[(size_t)n*AROW + k] = __float2bfloat16(0.f);
}

// h0 = node_emb[x].reshape(N,150) @ pre_lin_W + b ; also writes bf16 h into A
__global__ __launch_bounds__(256) void k_h0(const int* __restrict__ x,
        const float* __restrict__ node_emb, const float* __restrict__ plW,
        const float* __restrict__ plb, float* __restrict__ h,
        __hip_bfloat16* __restrict__ A){
    __shared__ float s_emb[21*75];
    __shared__ float s_W[150*75];
    __shared__ float s_b[75];
    int tid = threadIdx.x;
    for (int i = tid; i < 21*75; i += 256) s_emb[i] = node_emb[i];
    for (int i = tid; i < 150*75; i += 256) s_W[i] = plW[i];
    if (tid < 75) s_b[tid] = plb[tid];
    __syncthreads();
    for (int out = blockIdx.x*256 + tid; out < NN*75; out += gridDim.x*256){
        int n = out / 75, f = out - n*75;
        int x0 = x[2*n], x1 = x[2*n+1];
        float acc = s_b[f];
        const float* e0 = s_emb + x0*75;
        const float* e1 = s_emb + x1*75;
        #pragma unroll 5
        for (int k = 0; k < 75; k++)
            acc += e0[k]*s_W[k*75+f] + e1[k]*s_W[(75+k)*75+f];
        h[out] = acc;
        A[(size_t)n*AROW + 1536 + f] = __float2bfloat16(acc);
    }
}

__global__ void k_hist(const int* __restrict__ ei, int* __restrict__ cnt){
    int e = blockIdx.x*256 + threadIdx.x;
    if (e < NE) atomicAdd(&cnt[ei[NE + e]], 1);
}

__global__ void k_scan(const int* __restrict__ cnt, int* __restrict__ eoff){
    __shared__ int buf[256];
    __shared__ int carry;
    int tid = threadIdx.x;
    if (tid == 0){ carry = 0; eoff[0] = 0; }
    __syncthreads();
    for (int base = 0; base < NN; base += 256){
        int v = (base + tid < NN) ? cnt[base + tid] : 0;
        buf[tid] = v; __syncthreads();
        for (int off = 1; off < 256; off <<= 1){
            int t2 = (tid >= off) ? buf[tid - off] : 0;
            __syncthreads();
            buf[tid] += t2;
            __syncthreads();
        }
        int inc = buf[tid] + carry;
        if (base + tid < NN) eoff[base + tid + 1] = inc;
        __syncthreads();
        if (tid == 255) carry = inc;
        __syncthreads();
    }
}

__global__ void k_nodestats(const int* __restrict__ cnt, const int* __restrict__ eoff,
        float* __restrict__ invdeg, float* __restrict__ amp, float* __restrict__ att,
        int* __restrict__ cursor){
    int n = blockIdx.x*256 + threadIdx.x;
    if (n >= NN) return;
    int c = cnt[n];
    cursor[n] = eoff[n];
    float cf = (float)c;
    float dg = cf < 1.f ? 1.f : cf;
    invdeg[n] = 1.f / dg;
    float ld = logf(dg + 1.f);
    amp[n] = ld / ADL;
    att[n] = ADL / ld;
}

__global__ void k_scatter(const int* __restrict__ ei, const int* __restrict__ ea,
        int* __restrict__ cursor, int* __restrict__ esrc, int* __restrict__ ecombo){
    int e = blockIdx.x*256 + threadIdx.x;
    if (e >= NE) return;
    int src = ei[e], dst = ei[NE + e];
    int pos = atomicAdd(&cursor[dst], 1);
    esrc[pos] = src;
    ecombo[pos] = ea[2*e]*4 + ea[2*e+1];
}

// Fused: bx<313 P/Q (bf16); 313-317 Rlut; 318 zero stats
__global__ __launch_bounds__(384) void k_pq(const float* __restrict__ h,
        const float* __restrict__ preW, const float* __restrict__ preb,
        const float* __restrict__ edge_emb, const float* __restrict__ encW,
        const float* __restrict__ encb, int l,
        __hip_bfloat16* __restrict__ P, __hip_bfloat16* __restrict__ Q,
        float* __restrict__ Rlut, float* __restrict__ stats){
    __shared__ float smem[10675];
    int tid = threadIdx.x;
    int bx = blockIdx.x;

    if (bx == 318){
        for (int i = tid; i < 150; i += 384) stats[i] = 0.f;
        return;
    }
    if (bx >= 313){
        int t = bx - 313;
        float* s_encW = smem;
        float* s_ev   = smem + 3750;
        float* s_wc   = smem + 4950;
        float* s_ee   = smem + 10575;
        for (int i = tid; i < 3750; i += 384) s_encW[i] = encW[(size_t)l*3750 + i];
        for (int i = tid; i < 100; i += 384) s_ee[i] = edge_emb[i];
        const float* wcsrc = preW + (((size_t)(l*NT + t))*225 + 150)*75;
        for (int i = tid; i < 5625; i += 384) s_wc[i] = wcsrc[i];
        __syncthreads();
        for (int task = tid; task < 1200; task += 384){
            int b = task/75, m = task - 75*b;
            int a0 = b >> 2, a1 = b & 3;
            float s = encb[l*75 + m];
            for (int k = 0; k < 25; k++)
                s += s_ee[a0*25+k]*s_encW[k*75+m] + s_ee[a1*25+k]*s_encW[(25+k)*75+m];
            s_ev[task] = s;
        }
        __syncthreads();
        for (int task = tid; task < 1200; task += 384){
            int b = task/75, f = task - 75*b;
            float r = preb[((size_t)l*NT + t)*75 + f];
            const float* ev = s_ev + b*75;
            #pragma unroll 5
            for (int m = 0; m < 75; m++) r += ev[m]*s_wc[m*75 + f];
            Rlut[b*375 + t*75 + f] = r;
        }
        return;
    }

    float* h_t = smem;
    int base = bx*32;
    for (int idx = tid; idx < 32*75; idx += 384){
        int i = idx/75, m = idx - 75*i;
        int n = base + i;
        h_t[i*76 + m] = (n < NN) ? h[(size_t)n*75 + m] : 0.f;
    }
    __syncthreads();
    int j = tid;
    if (j >= 375) return;
    int t = j/75, f = j - 75*t;
    const float* wbase = preW + ((size_t)(l*NT + t))*225*75 + f;
    float accP[32], accQ[32];
    #pragma unroll
    for (int i = 0; i < 32; i++){ accP[i] = 0.f; accQ[i] = 0.f; }
    for (int m = 0; m < 72; m += 4){
        float wa0 = wbase[(m+0)*75], wa1 = wbase[(m+1)*75];
        float wa2 = wbase[(m+2)*75], wa3 = wbase[(m+3)*75];
        float wb0 = wbase[(75+m+0)*75], wb1 = wbase[(75+m+1)*75];
        float wb2 = wbase[(75+m+2)*75], wb3 = wbase[(75+m+3)*75];
        #pragma unroll
        for (int i = 0; i < 32; i++){
            const float4 hv = *(const float4*)&h_t[i*76 + m];
            accP[i] += hv.x*wa0 + hv.y*wa1 + hv.z*wa2 + hv.w*wa3;
            accQ[i] += hv.x*wb0 + hv.y*wb1 + hv.z*wb2 + hv.w*wb3;
        }
    }
    for (int m = 72; m < 75; m++){
        float wa = wbase[m*75], wb = wbase[(75+m)*75];
        #pragma unroll
        for (int i = 0; i < 32; i++){
            float v = h_t[i*76 + m];
            accP[i] += v*wa; accQ[i] += v*wb;
        }
    }
    for (int i = 0; i < 32; i++){
        int n = base + i;
        if (n < NN){
            P[(size_t)n*375 + j] = __float2bfloat16(accP[i]);
            Q[(size_t)n*375 + j] = __float2bfloat16(accQ[i]);
        }
    }
}

// grid (6, NN), block 64; writes agg into A matrix rows (stride AROW)
__global__ __launch_bounds__(64) void k_agg(const __hip_bfloat16* __restrict__ P,
        const __hip_bfloat16* __restrict__ Q, const float* __restrict__ Rlut,
        const int* __restrict__ eoff, const int* __restrict__ esrc,
        const int* __restrict__ ecombo, const float* __restrict__ invdeg,
        __hip_bfloat16* __restrict__ A){
    int n = blockIdx.y;
    int j = blockIdx.x*64 + threadIdx.x;
    if (j >= 375) return;
    int lo = eoff[n], hi = eoff[n+1];
    float p = bf2f(P[(size_t)n*375 + j]);
    float sum = 0.f, sq = 0.f, mn = 3.4e38f, mx = -3.4e38f;
    int e = lo;
    for (; e + 8 <= hi; e += 8){
        int s0 = esrc[e],   s1 = esrc[e+1], s2 = esrc[e+2], s3 = esrc[e+3];
        int s4 = esrc[e+4], s5 = esrc[e+5], s6 = esrc[e+6], s7 = esrc[e+7];
        int c0 = ecombo[e],   c1 = ecombo[e+1], c2 = ecombo[e+2], c3 = ecombo[e+3];
        int c4 = ecombo[e+4], c5 = ecombo[e+5], c6 = ecombo[e+6], c7 = ecombo[e+7];
        float q0 = bf2f(Q[(size_t)s0*375 + j]);
        float q1 = bf2f(Q[(size_t)s1*375 + j]);
        float q2 = bf2f(Q[(size_t)s2*375 + j]);
        float q3 = bf2f(Q[(size_t)s3*375 + j]);
        float q4 = bf2f(Q[(size_t)s4*375 + j]);
        float q5 = bf2f(Q[(size_t)s5*375 + j]);
        float q6 = bf2f(Q[(size_t)s6*375 + j]);
        float q7 = bf2f(Q[(size_t)s7*375 + j]);
        float r0 = Rlut[c0*375 + j], r1 = Rlut[c1*375 + j];
        float r2 = Rlut[c2*375 + j], r3 = Rlut[c3*375 + j];
        float r4 = Rlut[c4*375 + j], r5 = Rlut[c5*375 + j];
        float r6 = Rlut[c6*375 + j], r7 = Rlut[c7*375 + j];
        float m0 = p + q0 + r0, m1 = p + q1 + r1;
        float m2 = p + q2 + r2, m3 = p + q3 + r3;
        float m4 = p + q4 + r4, m5 = p + q5 + r5;
        float m6 = p + q6 + r6, m7 = p + q7 + r7;
        sum += (m0 + m1 + m2 + m3) + (m4 + m5 + m6 + m7);
        sq  += (m0*m0 + m1*m1 + m2*m2 + m3*m3) + (m4*m4 + m5*m5 + m6*m6 + m7*m7);
        mn = fminf(mn, fminf(fminf(fminf(m0,m1), fminf(m2,m3)),
                             fminf(fminf(m4,m5), fminf(m6,m7))));
        mx = fmaxf(mx, fmaxf(fmaxf(fmaxf(m0,m1), fmaxf(m2,m3)),
                             fmaxf(fmaxf(m4,m5), fmaxf(m6,m7))));
    }
    for (; e < hi; e++){
        int s = esrc[e], cm = ecombo[e];
        float m = p + bf2f(Q[(size_t)s*375 + j]) + Rlut[cm*375 + j];
        sum += m; sq += m*m;
        mn = fminf(mn, m); mx = fmaxf(mx, m);
    }
    float id = invdeg[n];
    bool has = hi > lo;
    float mean = sum*id;
    float msq  = sq*id;
    float var = msq - mean*mean; var = var > 0.f ? var : 0.f;
    float sd = sqrtf(var + 1e-5f);
    float mnv = has ? mn : 0.f;
    float mxv = has ? mx : 0.f;
    int t = j/75, f = j - 75*t;
    __hip_bfloat16* a = A + (size_t)n*AROW + t*300;
    a[f]      = __float2bfloat16(mean);
    a[75+f]   = __float2bfloat16(mnv);
    a[150+f]  = __float2bfloat16(mxv);
    a[225+f]  = __float2bfloat16(sd);
}

// Build BT[3][80][1632] bf16: W2[t,c,o] = sum_f postW[l,t,c,f]*linW[l,t*15+f,o]
// B1: c=75+kk (+ h-part rows summed over t); B2: c=375+kk; B3: c=675+kk.
// Block 1530 computes biasc[o] = sum postb*linW + linb.
__global__ __launch_bounds__(256) void k_prep(const float* __restrict__ postW,
        const float* __restrict__ postb, const float* __restrict__ linW,
        const float* __restrict__ linb, int l,
        __hip_bfloat16* __restrict__ BT, float* __restrict__ biasc){
    int tid = threadIdx.x;
    if (blockIdx.x == 1530){
        if (tid < 80){
            float s = (tid < 75) ? linb[l*75 + tid] : 0.f;
            if (tid < 75)
                for (int tf = 0; tf < 75; tf++)
                    s += postb[l*75 + tf]*linW[(size_t)l*5625 + tf*75 + tid];
            biasc[tid] = s;
        }
        return;
    }
    __shared__ float s_lin[5625];
    for (int i = tid; i < 5625; i += 256) s_lin[i] = linW[(size_t)l*5625 + i];
    __syncthreads();
    int idx = blockIdx.x*256 + tid;          // < 3*80*1632 = 391680
    int mat = idx / (80*AROW);
    int rem = idx - mat*(80*AROW);
    int o = rem / AROW;
    int k = rem - o*AROW;
    float v = 0.f;
    if (o < 75){
        if (k < 1500){
            int t = k / 300, kk = k - t*300;
            int c = (mat == 0 ? 75 : (mat == 1 ? 375 : 675)) + kk;
            const float* pw = postW + (((size_t)(l*NT + t))*975 + c)*15;
            const float* lw = s_lin + t*15*75 + o;
            #pragma unroll
            for (int f = 0; f < 15; f++) v += pw[f]*lw[f*75];
        } else if (k >= 1536 && k < 1611 && mat == 0){
            int c = k - 1536;
            for (int t = 0; t < 5; t++){
                const float* pw = postW + (((size_t)(l*NT + t))*975 + c)*15;
                const float* lw = s_lin + t*15*75 + o;
                #pragma unroll
                for (int f = 0; f < 15; f++) v += pw[f]*lw[f*75];
            }
        }
    }
    BT[idx] = __float2bfloat16(v);
}

// MFMA GEMM: hc[10000,75] = A[10000,1632] x {B1,B2,B3}[1632,80] combined with
// amp/att/bias; fused BN-stat reduction. Block = 16 M-rows, 4 waves split K.
// Fragments (guide-verified): A: m=lane&15, k=quad*8+j; B: n=lane&15, k=quad*8+j;
// C/D: col=lane&15, row=quad*4+reg.
__global__ __launch_bounds__(256) void k_gemm(const __hip_bfloat16* __restrict__ A,
        const __hip_bfloat16* __restrict__ BT, const float* __restrict__ biasc,
        const float* __restrict__ amp, const float* __restrict__ att,
        float* __restrict__ hc, float* __restrict__ stats){
    __shared__ float scratch[4*16*80];   // 20.5 KB
    __shared__ float comb[3*16*80];      // 15.4 KB
    int tid = threadIdx.x;
    int wave = tid >> 6;
    int lane = tid & 63;
    int nb = blockIdx.x;                 // 0..624
    int mrow = lane & 15;
    int q = lane >> 4;
    int n0 = nb*16;

    f32x4 acc[3][5];
    #pragma unroll
    for (int mt = 0; mt < 3; mt++)
        #pragma unroll
        for (int nt = 0; nt < 5; nt++)
            acc[mt][nt] = (f32x4){0.f, 0.f, 0.f, 0.f};

    int k0 = wave*13;
    int k1 = (wave == 3) ? 51 : k0 + 13;
    const __hip_bfloat16* arow_p = A + (size_t)(n0 + mrow)*AROW + q*8;
    for (int ks = k0; ks < k1; ks++){
        bf16x8 afrag = *(const bf16x8*)(arow_p + (size_t)ks*32);
        #pragma unroll
        for (int mt = 0; mt < 3; mt++){
            const __hip_bfloat16* bbase = BT + ((size_t)mt*80 + mrow)*AROW + q*8 + (size_t)ks*32;
            #pragma unroll
            for (int nt = 0; nt < 5; nt++){
                bf16x8 bfrag = *(const bf16x8*)(bbase + (size_t)nt*16*AROW);
                acc[mt][nt] = __builtin_amdgcn_mfma_f32_16x16x32_bf16(
                                  afrag, bfrag, acc[mt][nt], 0, 0, 0);
            }
        }
    }
    // cross-wave K-reduction, mat by mat
    for (int mt = 0; mt < 3; mt++){
        #pragma unroll
        for (int nt = 0; nt < 5; nt++)
            #pragma unroll
            for (int r = 0; r < 4; r++)
                scratch[(wave*16 + q*4 + r)*80 + nt*16 + (lane & 15)] = acc[mt][nt][r];
        __syncthreads();
        for (int i = tid; i < 16*80; i += 256)
            comb[mt*1280 + i] = scratch[i] + scratch[1280 + i]
                              + scratch[2560 + i] + scratch[3840 + i];
        __syncthreads();
    }
    // epilogue: hc = C1 + amp*C2 + att*C3 + biasc
    for (int i = tid; i < 16*80; i += 256){
        int r = i / 80, o = i - r*80;
        int n = n0 + r;
        float v = comb[i] + amp[n]*comb[1280 + i] + att[n]*comb[2560 + i] + biasc[o];
        scratch[i] = v;
        if (o < 75) hc[(size_t)n*75 + o] = v;
    }
    __syncthreads();
    if (tid < 75){
        float s1 = 0.f, s2 = 0.f;
        #pragma unroll
        for (int r = 0; r < 16; r++){
            float v = scratch[r*80 + tid];
            s1 += v; s2 += v*v;
        }
        atomicAdd(&stats[tid], s1);
        atomicAdd(&stats[75 + tid], s2);
    }
}

__global__ void k_bnapply(const float* __restrict__ hc, const float* __restrict__ stats,
        const float* __restrict__ bng, const float* __restrict__ bnb, int l,
        float* __restrict__ h, __hip_bfloat16* __restrict__ A){
    int idx = blockIdx.x*256 + threadIdx.x;
    if (idx >= NN*75) return;
    int col = idx % 75;
    int n = idx / 75;
    float mu = stats[col]*(1.0f/NN);
    float var = stats[75+col]*(1.0f/NN) - mu*mu;
    float inv = rsqrtf(var + 1e-5f);
    float v = (hc[idx] - mu)*inv*bng[l*75+col] + bnb[l*75+col];
    v = v > 0.f ? v : 0.f;
    h[idx] = v;
    A[(size_t)n*AROW + 1536 + col] = __float2bfloat16(v);
}

__global__ __launch_bounds__(256) void k_pool(const float* __restrict__ h,
        const int* __restrict__ batch, float* __restrict__ gpool){
    int g = blockIdx.x, tid = threadIdx.x;
    int lo = 0, hi = NN;
    while (lo < hi){ int mid = (lo+hi)>>1; if (batch[mid] < g) lo = mid+1; else hi = mid; }
    int start = lo;
    lo = start; hi = NN;
    while (lo < hi){ int mid = (lo+hi)>>1; if (batch[mid] < g+1) lo = mid+1; else hi = mid; }
    int end = lo;
    __shared__ float red[225];
    if (tid < 225){
        int col = tid % 75, rep = tid / 75;
        float acc = 0.f;
        for (int i = start + rep; i < end; i += 3) acc += h[(size_t)i*75 + col];
        red[tid] = acc;
    }
    __syncthreads();
    if (tid < 75) gpool[g*75 + tid] = red[tid] + red[75+tid] + red[150+tid];
}

__global__ __launch_bounds__(256) void k_mlp(const float* __restrict__ gpool,
        const float* __restrict__ W1, const float* __restrict__ b1,
        const float* __restrict__ W2, const float* __restrict__ b2,
        const float* __restrict__ W3, const float* __restrict__ b3,
        float* __restrict__ out){
    __shared__ float w1[75*50];
    __shared__ float w2[50*25];
    __shared__ float gp[8*75];
    __shared__ float t1[8*50];
    __shared__ float t2[8*25];
    int tid = threadIdx.x;
    int gbase = blockIdx.x*8;
    for (int i = tid; i < 75*50; i += 256) w1[i] = W1[i];
    for (int i = tid; i < 50*25; i += 256) w2[i] = W2[i];
    for (int i = tid; i < 8*75; i += 256) gp[i] = gpool[gbase*75 + i];
    __syncthreads();
    for (int task = tid; task < 8*50; task += 256){
        int g = task/50, j = task - 50*g;
        float s = b1[j];
        const float* gv = gp + g*75;
        #pragma unroll 5
        for (int k = 0; k < 75; k++) s += gv[k]*w1[k*50+j];
        t1[task] = s > 0.f ? s : 0.f;
    }
    __syncthreads();
    for (int task = tid; task < 8*25; task += 256){
        int g = task/25, j = task - 25*g;
        float s = b2[j];
        const float* tv = t1 + g*50;
        #pragma unroll 5
        for (int k = 0; k < 50; k++) s += tv[k]*w2[k*25+j];
        t2[task] = s > 0.f ? s : 0.f;
    }
    __syncthreads();
    if (tid < 8){
        float s = b3[0];
        const float* tv = t2 + tid*25;
        #pragma unroll
        for (int k = 0; k < 25; k++) s += tv[k]*W3[k];
        out[gbase + tid] = s;
    }
}

extern "C" void kernel_launch(void* const* d_in, const int* in_sizes, int n_in,
                              void* d_out, int out_size, void* d_ws, size_t ws_size,
                              hipStream_t stream){
    const int* x          = (const int*)d_in[0];
    const int* edge_index = (const int*)d_in[1];
    const int* edge_attr  = (const int*)d_in[2];
    const int* batch      = (const int*)d_in[3];
    const float* node_emb = (const float*)d_in[4];
    const float* edge_emb = (const float*)d_in[5];
    const float* pre_lin_W= (const float*)d_in[6];
    const float* pre_lin_b= (const float*)d_in[7];
    const float* encW     = (const float*)d_in[8];
    const float* encb     = (const float*)d_in[9];
    const float* preW     = (const float*)d_in[10];
    const float* preb     = (const float*)d_in[11];
    const float* postW    = (const float*)d_in[12];
    const float* postb    = (const float*)d_in[13];
    const float* linW     = (const float*)d_in[14];
    const float* linb     = (const float*)d_in[15];
    const float* bng      = (const float*)d_in[16];
    const float* bnb      = (const float*)d_in[17];
    const float* mlpW1    = (const float*)d_in[18];
    const float* mlpb1    = (const float*)d_in[19];
    const float* mlpW2    = (const float*)d_in[20];
    const float* mlpb2    = (const float*)d_in[21];
    const float* mlpW3    = (const float*)d_in[22];
    const float* mlpb3    = (const float*)d_in[23];

    float* ws = (float*)d_ws;
    float* h      = ws + OFF_H;
    float* hc     = ws + OFF_HC;
    __hip_bfloat16* P = (__hip_bfloat16*)(ws + OFF_P);
    __hip_bfloat16* Q = (__hip_bfloat16*)(ws + OFF_Q);
    __hip_bfloat16* A = (__hip_bfloat16*)(ws + OFF_A);
    __hip_bfloat16* BT = (__hip_bfloat16*)(ws + OFF_BT);
    float* biasc  = ws + OFF_BIASC;
    float* Rlut   = ws + OFF_RLUT;
    float* invdeg = ws + OFF_INVDEG;
    float* amp    = ws + OFF_AMP;
    float* att    = ws + OFF_ATT;
    float* stats  = ws + OFF_STATS;
    float* gpool  = ws + OFF_GPOOL;
    int* iw     = (int*)(ws + OFF_INT);
    int* cnt    = iw;
    int* eoff   = cnt + NN;        // NN+1
    int* cursor = eoff + NN + 2;
    int* esrc   = cursor + NN;
    int* ecombo = esrc + NE;

    k_zero_cnt<<<40, 256, 0, stream>>>(cnt);
    k_zpad<<<(NN*57 + 255)/256, 256, 0, stream>>>(A);
    k_h0<<<640, 256, 0, stream>>>(x, node_emb, pre_lin_W, pre_lin_b, h, A);
    k_hist<<<625, 256, 0, stream>>>(edge_index, cnt);
    k_scan<<<1, 256, 0, stream>>>(cnt, eoff);
    k_nodestats<<<40, 256, 0, stream>>>(cnt, eoff, invdeg, amp, att, cursor);
    k_scatter<<<625, 256, 0, stream>>>(edge_index, edge_attr, cursor, esrc, ecombo);

    for (int l = 0; l < NL; l++){
        k_pq<<<319, 384, 0, stream>>>(h, preW, preb, edge_emb, encW, encb, l,
                                      P, Q, Rlut, stats);
        k_agg<<<dim3(6, NN), 64, 0, stream>>>(P, Q, Rlut, eoff, esrc, ecombo, invdeg, A);
        k_prep<<<1531, 256, 0, stream>>>(postW, postb, linW, linb, l, BT, biasc);
        k_gemm<<<625, 256, 0, stream>>>(A, BT, biasc, amp, att, hc, stats);
        k_bnapply<<<2930, 256, 0, stream>>>(hc, stats, bng, bnb, l, h, A);
    }

    k_pool<<<NG, 256, 0, stream>>>(h, batch, gpool);
    k_mlp<<<8, 256, 0, stream>>>(gpool, mlpW1, mlpb1, mlpW2, mlpb2, mlpW3, mlpb3, (float*)d_out);
}